// Round 6
// baseline (378.124 us; speedup 1.0000x reference)
//
#include <hip/hip_runtime.h>

#define B_    4
#define N_    11
#define D_    589824L      // 64*96*96 floats per row
#define NP2   66           // upper-tri incl diagonal (e2 pairs)
#define NP1   55           // strict upper-tri (e1 pairs)
#define NSH   4            // atomic shards
#define TPBAT 576L         // tiles per batch (1024 cols each)
#define TROW  1024L        // floats per tile row
#define TSZ   (N_ * TROW)  // floats per tile = 11264
#define E1W0  12           // direct-path wave split (r5, fallback only)

typedef float nfloat4 __attribute__((ext_vector_type(4)));

// ---------------------------------------------------------------------------
// wave64 sum-reduction via DPP (pure VALU). Result valid in lane 63. (proven r1-r5)
// ---------------------------------------------------------------------------
__device__ __forceinline__ float wave_red_add(float x) {
    int t;
    t = __builtin_amdgcn_update_dpp(0, __float_as_int(x), 0x111, 0xf, 0xf, false); x += __int_as_float(t);
    t = __builtin_amdgcn_update_dpp(0, __float_as_int(x), 0x112, 0xf, 0xf, false); x += __int_as_float(t);
    t = __builtin_amdgcn_update_dpp(0, __float_as_int(x), 0x114, 0xf, 0xf, false); x += __int_as_float(t);
    t = __builtin_amdgcn_update_dpp(0, __float_as_int(x), 0x118, 0xf, 0xf, false); x += __int_as_float(t);
    t = __builtin_amdgcn_update_dpp(0, __float_as_int(x), 0x142, 0xa, 0xf, false); x += __int_as_float(t);
    t = __builtin_amdgcn_update_dpp(0, __float_as_int(x), 0x143, 0xc, 0xf, false); x += __int_as_float(t);
    return x;
}

// ---------------------------------------------------------------------------
// K0: pack x -> tile-major y[bz][tile][n][1024]. Reads x PERFECTLY LINEARLY
// (the proven-fast pattern); writes coalesced 4KB chunks, fire-and-forget.
// grid (144, N_, nb), 256 thr. Each block: 4096 floats of one row -> 4 tiles.
// ---------------------------------------------------------------------------
__global__ __launch_bounds__(256) void pack_kernel(const float* __restrict__ x,
                                                   float* __restrict__ y, int b0) {
    const int bx = blockIdx.x, n = blockIdx.y, bz = blockIdx.z, t = threadIdx.x;
    const float* xr = x + ((long)(b0 + bz) * N_ + n) * D_ + (long)bx * 4096 + t * 4;
    float* yb = y + (((long)bz * TPBAT + bx * 4) * N_ + n) * TROW + t * 4;
#pragma unroll
    for (int k = 0; k < 4; ++k) {
        const nfloat4 v = __builtin_nontemporal_load(
            reinterpret_cast<const nfloat4*>(xr + (long)k * TROW));
        *reinterpret_cast<nfloat4*>(yb + (long)k * TSZ) = v;   // next tile
    }
}

// ---------------------------------------------------------------------------
// K1: pairwise reductions from packed tiles (contiguous 45KB, L3-hot).
// grid (144, nb), 256 thr; each block does 4 consecutive tiles, full 121
// accumulators per thread (r0-proven register budget, ~140 VGPR, no clamp).
// DPP tail amortized over 4 tiles; atomics sharded by bx&3.
// ---------------------------------------------------------------------------
__global__ __launch_bounds__(256) void reduce_kernel(const float* __restrict__ y,
                                                     double* __restrict__ e2s,   // [NSH][B_][NP2]
                                                     double* __restrict__ e1s,   // [NSH][B_][NP1]
                                                     int b0) {
    const int bx = blockIdx.x, bz = blockIdx.y, t = threadIdx.x;
    const int lane = t & 63, sh = bx & (NSH - 1), b = b0 + bz;

    float acc2[NP2], acc1[NP1];
#pragma unroll
    for (int p = 0; p < NP2; ++p) acc2[p] = 0.f;
#pragma unroll
    for (int p = 0; p < NP1; ++p) acc1[p] = 0.f;

    const float* base = y + ((long)bz * TPBAT + (long)bx * 4) * TSZ + t * 4;
#pragma unroll 1
    for (int tt = 0; tt < 4; ++tt) {
        const float* tb = base + (long)tt * TSZ;
        float4 v[N_];
#pragma unroll
        for (int m = 0; m < N_; ++m)
            v[m] = *reinterpret_cast<const float4*>(tb + (long)m * TROW);
        int p = 0, q = 0;
#pragma unroll
        for (int i = 0; i < N_; ++i) {
#pragma unroll
            for (int j = i; j < N_; ++j, ++p) {
                acc2[p] += v[i].x * v[j].x + v[i].y * v[j].y +
                           v[i].z * v[j].z + v[i].w * v[j].w;
                if (j > i) {
                    acc1[q] += fabsf(v[i].x - v[j].x) + fabsf(v[i].y - v[j].y) +
                               fabsf(v[i].z - v[j].z) + fabsf(v[i].w - v[j].w);
                    ++q;
                }
            }
        }
    }

#pragma unroll
    for (int p = 0; p < NP2; ++p) {
        const float s = wave_red_add(acc2[p]);
        if (lane == 63) atomicAdd(&e2s[(sh * B_ + b) * NP2 + p], (double)s);
    }
#pragma unroll
    for (int p = 0; p < NP1; ++p) {
        const float s = wave_red_add(acc1[p]);
        if (lane == 63) atomicAdd(&e1s[(sh * B_ + b) * NP1 + p], (double)s);
    }
}

// ---------------------------------------------------------------------------
// K2: sum shards; E = e1*e2 (symmetric, diag 0); M = gamma*softmax(max-E)+I.
// (proven r5) grid (nb), b = b0 + blockIdx.x.
// ---------------------------------------------------------------------------
__global__ __launch_bounds__(128) void attn_kernel(const double* __restrict__ e2s,
                                                   const double* __restrict__ e1s,
                                                   const float* __restrict__ gamma,
                                                   float* __restrict__ Mws, int b0) {
    const int b = b0 + blockIdx.x, t = threadIdx.x;
    __shared__ double E[N_][N_];
    if (t < NP2) {
        int rem = t, i = 0, cnt = N_;
        while (rem >= cnt) { rem -= cnt; --cnt; ++i; }
        const int j = i + rem;
        double e = 0.0;
        if (j > i) {
            const int q = i * (2 * N_ - 1 - i) / 2 + (j - i - 1);
            double s2 = 0.0, s1 = 0.0;
#pragma unroll
            for (int sh = 0; sh < NSH; ++sh) {
                s2 += e2s[(sh * B_ + b) * NP2 + t];
                s1 += e1s[(sh * B_ + b) * NP1 + q];
            }
            e = s1 * s2;
        }
        E[i][j] = e;
        E[j][i] = e;
    }
    __syncthreads();
    if (t < N_) {
        const int i = t;
        double mn = E[i][0];
#pragma unroll
        for (int j = 1; j < N_; ++j) mn = fmin(mn, E[i][j]);
        double ex[N_], s = 0.0;
#pragma unroll
        for (int j = 0; j < N_; ++j) { ex[j] = exp(mn - E[i][j]); s += ex[j]; }
        const float g = gamma[0];
        const double inv = 1.0 / s;
#pragma unroll
        for (int j = 0; j < N_; ++j)
            Mws[(b * N_ + i) * N_ + j] = (float)(ex[j] * inv) * g + (i == j ? 1.0f : 0.0f);
    }
}

// ---------------------------------------------------------------------------
// K3: out[n,d] = sum_m M[n][m]*y[tile][m]. Tile reads contiguous & L3-hot;
// out written NT (fire-and-forget; strided writes proven fine in r1).
// grid (TPBAT, nb), 256 thr.
// ---------------------------------------------------------------------------
__global__ __launch_bounds__(256) void apply_kernel(const float* __restrict__ y,
                                                    const float* __restrict__ Mws,
                                                    float* __restrict__ out, int b0) {
    const int tile = blockIdx.x, bz = blockIdx.y, t = threadIdx.x;
    const int b = b0 + bz;
    __shared__ float M[N_ * N_];
    if (t < N_ * N_) M[t] = Mws[b * N_ * N_ + t];
    __syncthreads();

    const float* tb = y + ((long)bz * TPBAT + tile) * TSZ + t * 4;
    float4 v[N_];
#pragma unroll
    for (int m = 0; m < N_; ++m)
        v[m] = *reinterpret_cast<const float4*>(tb + (long)m * TROW);

    float* ob = out + (long)b * N_ * D_ + (long)tile * TROW + t * 4;
#pragma unroll 1
    for (int n = 0; n < N_; ++n) {
        float ox = 0.f, oy = 0.f, oz = 0.f, ow = 0.f;
#pragma unroll
        for (int m = 0; m < N_; ++m) {
            const float w = M[n * N_ + m];
            ox += w * v[m].x; oy += w * v[m].y;
            oz += w * v[m].z; ow += w * v[m].w;
        }
        nfloat4 o; o[0] = ox; o[1] = oy; o[2] = oz; o[3] = ow;
        __builtin_nontemporal_store(o, reinterpret_cast<nfloat4*>(ob + (long)n * D_));
    }
}

// ---------------------------------------------------------------------------
// Direct fallback (no workspace for pack): r5 kernels, proven correct.
// ---------------------------------------------------------------------------
__global__ __launch_bounds__(128) void reduce_direct(const float* __restrict__ src,
                                                     double* __restrict__ e2s,
                                                     double* __restrict__ e1s) {
    const int b = blockIdx.y, c = blockIdx.x;
    const int t = threadIdx.x, wave = t >> 6, lane = t & 63;
    const int sh = c & (NSH - 1);
    const float* sb = src + (long)b * N_ * D_;
    const long col0 = (long)c * 1024 + lane * 4;

    if (wave == 0) {
        float a2[NP2], a1[E1W0];
#pragma unroll
        for (int p = 0; p < NP2; ++p) a2[p] = 0.f;
#pragma unroll
        for (int p = 0; p < E1W0; ++p) a1[p] = 0.f;
#pragma unroll 1
        for (int it = 0; it < 4; ++it) {
            const long d = col0 + it * 256;
            float4 v[N_];
#pragma unroll
            for (int m = 0; m < N_; ++m)
                v[m] = *reinterpret_cast<const float4*>(sb + (long)m * D_ + d);
            int p = 0;
#pragma unroll
            for (int i = 0; i < N_; ++i)
#pragma unroll
                for (int j = i; j < N_; ++j, ++p)
                    a2[p] += v[i].x * v[j].x + v[i].y * v[j].y +
                             v[i].z * v[j].z + v[i].w * v[j].w;
            int q = 0;
#pragma unroll
            for (int i = 0; i < N_; ++i)
#pragma unroll
                for (int j = i + 1; j < N_; ++j, ++q)
                    if (q < E1W0)
                        a1[q] += fabsf(v[i].x - v[j].x) + fabsf(v[i].y - v[j].y) +
                                 fabsf(v[i].z - v[j].z) + fabsf(v[i].w - v[j].w);
        }
#pragma unroll
        for (int p = 0; p < NP2; ++p) {
            const float s = wave_red_add(a2[p]);
            if (lane == 63) atomicAdd(&e2s[(sh * B_ + b) * NP2 + p], (double)s);
        }
#pragma unroll
        for (int p = 0; p < E1W0; ++p) {
            const float s = wave_red_add(a1[p]);
            if (lane == 63) atomicAdd(&e1s[(sh * B_ + b) * NP1 + p], (double)s);
        }
    } else {
        float a1[NP1 - E1W0];
#pragma unroll
        for (int p = 0; p < NP1 - E1W0; ++p) a1[p] = 0.f;
#pragma unroll 1
        for (int it = 0; it < 4; ++it) {
            const long d = col0 + it * 256;
            float4 v[N_];
#pragma unroll
            for (int m = 0; m < N_; ++m)
                v[m] = *reinterpret_cast<const float4*>(sb + (long)m * D_ + d);
            int q = 0;
#pragma unroll
            for (int i = 0; i < N_; ++i)
#pragma unroll
                for (int j = i + 1; j < N_; ++j, ++q)
                    if (q >= E1W0)
                        a1[q - E1W0] += fabsf(v[i].x - v[j].x) + fabsf(v[i].y - v[j].y) +
                                        fabsf(v[i].z - v[j].z) + fabsf(v[i].w - v[j].w);
        }
#pragma unroll
        for (int p = 0; p < NP1 - E1W0; ++p) {
            const float s = wave_red_add(a1[p]);
            if (lane == 63) atomicAdd(&e1s[(sh * B_ + b) * NP1 + E1W0 + p], (double)s);
        }
    }
}

__global__ __launch_bounds__(256) void apply_direct(const float* __restrict__ src,
                                                    const float* __restrict__ Mws,
                                                    float* __restrict__ out) {
    const int b = blockIdx.y, c = blockIdx.x, t = threadIdx.x;
    __shared__ float M[N_ * N_];
    if (t < N_ * N_) M[t] = Mws[b * N_ * N_ + t];
    __syncthreads();

    const float* sb = src + (long)b * N_ * D_;
    float* ob = out + (long)b * N_ * D_;
    const long d = (long)c * 1024 + t * 4;

    float4 v[N_];
#pragma unroll
    for (int m = 0; m < N_; ++m)
        v[m] = *reinterpret_cast<const float4*>(sb + (long)m * D_ + d);

#pragma unroll 1
    for (int n = 0; n < N_; ++n) {
        float ox = 0.f, oy = 0.f, oz = 0.f, ow = 0.f;
#pragma unroll
        for (int m = 0; m < N_; ++m) {
            const float w = M[n * N_ + m];
            ox += w * v[m].x; oy += w * v[m].y;
            oz += w * v[m].z; ow += w * v[m].w;
        }
        nfloat4 o; o[0] = ox; o[1] = oy; o[2] = oz; o[3] = ow;
        __builtin_nontemporal_store(o, reinterpret_cast<nfloat4*>(ob + (long)n * D_ + d));
    }
}

// ---------------------------------------------------------------------------
extern "C" void kernel_launch(void* const* d_in, const int* in_sizes, int n_in,
                              void* d_out, int out_size, void* d_ws, size_t ws_size,
                              hipStream_t stream) {
    const float* x     = (const float*)d_in[0];
    const float* gamma = (const float*)d_in[1];
    float* out         = (float*)d_out;

    const size_t HDR = 32768;
    double* e2s = (double*)d_ws;                      // [NSH][B_][NP2]
    double* e1s = e2s + NSH * B_ * NP2;               // [NSH][B_][NP1]
    float*  Mws = (float*)(e1s + NSH * B_ * NP1);     // [B_][121]
    float*  y   = (float*)((char*)d_ws + HDR);        // packed tiles

    const size_t Y1 = (size_t)TPBAT * TSZ * sizeof(float);   // 25.95 MB per batch
    const size_t YF = (size_t)B_ * Y1;                       // 103.8 MB all batches

    // zero fp64 accumulator shards (ws is poisoned before every launch)
    hipMemsetAsync(d_ws, 0, (size_t)(NSH * B_ * (NP2 + NP1)) * sizeof(double), stream);

    if (ws_size >= HDR + YF) {
        // full pack: 5 launches
        pack_kernel<<<dim3(144, N_, B_), 256, 0, stream>>>(x, y, 0);
        reduce_kernel<<<dim3(144, B_), 256, 0, stream>>>(y, e2s, e1s, 0);
        attn_kernel<<<B_, 128, 0, stream>>>(e2s, e1s, gamma, Mws, 0);
        apply_kernel<<<dim3(TPBAT, B_), 256, 0, stream>>>(y, Mws, out, 0);
    } else if (ws_size >= HDR + Y1) {
        // per-batch sweeps reusing one y buffer (stream order serializes)
        for (int b = 0; b < B_; ++b) {
            pack_kernel<<<dim3(144, N_, 1), 256, 0, stream>>>(x, y, b);
            reduce_kernel<<<dim3(144, 1), 256, 0, stream>>>(y, e2s, e1s, b);
            attn_kernel<<<1, 128, 0, stream>>>(e2s, e1s, gamma, Mws, b);
            apply_kernel<<<dim3(TPBAT, 1), 256, 0, stream>>>(y, Mws, out, b);
        }
    } else {
        // direct path (r5, proven)
        reduce_direct<<<dim3(576, B_), 128, 0, stream>>>(x, e2s, e1s);
        attn_kernel<<<B_, 128, 0, stream>>>(e2s, e1s, gamma, Mws, 0);
        apply_direct<<<dim3(576, B_), 256, 0, stream>>>(x, Mws, out);
    }
}